// Round 9
// baseline (224.616 us; speedup 1.0000x reference)
//
#include <hip/hip_runtime.h>

// Problem dims (fixed by setup_inputs)
#define BATCH 4
#define HH 128
#define WW 128
#define CC 128
#define BIN 64
#define NPIX (BATCH * HH * WW)   // 65536

typedef short bf16x8 __attribute__((ext_vector_type(8)));
typedef float f32x4 __attribute__((ext_vector_type(4)));

// round-to-nearest-even bf16 bits of f
__device__ __forceinline__ unsigned bf_hi(float f) {
    unsigned u = __float_as_uint(f);
    return (u + 0x7fffu + ((u >> 16) & 1u)) >> 16;
}
// A-operand split: per c, k' slots [4c..4c+3] = [xh, xh, xl, xl]
__device__ __forceinline__ uint2 split_aa(float f) {
    unsigned hb = bf_hi(f);
    float lo = f - __uint_as_float(hb << 16);
    unsigned lb = bf_hi(lo);
    return make_uint2(hb | (hb << 16), lb | (lb << 16));
}
// B-operand split: per c, k' slots = [wh, wl, wh, wl] -> same uint twice
__device__ __forceinline__ unsigned split_b(float f) {
    unsigned hb = bf_hi(f);
    float lo = f - __uint_as_float(hb << 16);
    unsigned lb = bf_hi(lo);
    return hb | (lb << 16);
}

// ---------------------------------------------------------------------------
// Kernel 0: W pre-split. W_main/W_ref (128x128 fp32) -> split-bf16 BT LDS
// images: per matrix 8 chunks x [128 d][72 shorts] (64 k' + 8 zero pad),
// exactly the BT layout conv reads. 288KB, written into d_out scratch
// (conv consumes it before attn overwrites d_out). Saves conv ~40% of
// staging VALU (8 split_b/thread/chunk) + 8 scattered scalar loads.
// ---------------------------------------------------------------------------
__global__ __launch_bounds__(256)
void wsplit_kernel(const float* __restrict__ Wm, const float* __restrict__ Wr,
                   unsigned short* __restrict__ img) {
    const int row = blockIdx.x * 256 + threadIdx.x;   // 0..2047
    const int m = row >> 10;                          // matrix
    const int rr = row & 1023;
    const int chunk = rr >> 7, d = rr & 127;
    const float* W = m ? Wr : Wm;
    unsigned short* rp = img + ((size_t)(m * 8 + chunk) * 128 + d) * 72;
#pragma unroll
    for (int cg = 0; cg < 4; ++cg) {
        const int c = chunk * 16 + cg * 4;
        unsigned b0 = split_b(W[(size_t)(c + 0) * CC + d]);
        unsigned b1 = split_b(W[(size_t)(c + 1) * CC + d]);
        unsigned b2 = split_b(W[(size_t)(c + 2) * CC + d]);
        unsigned b3 = split_b(W[(size_t)(c + 3) * CC + d]);
        *(uint4*)(rp + cg * 16)     = make_uint4(b0, b0, b1, b1);
        *(uint4*)(rp + cg * 16 + 8) = make_uint4(b2, b2, b3, b3);
    }
    *(uint4*)(rp + 64) = make_uint4(0, 0, 0, 0);      // pad
}

// ---------------------------------------------------------------------------
// Kernel 1: 1x1 conv == GEMM via split-bf16 MFMA.
// v8: B-tile comes from the pre-split W image via 18x global_load_lds
// (1KB each) issued at phase start — L2-hot (128 blocks reuse it), latency
// hidden under A-staging. A-staging (X fp32->split-bf16) unchanged,
// depth-1 register prefetch, straight-line (no address-taken arrays —
// round-5 lesson). LDS 36.8KB -> 4 blocks/CU.
// ---------------------------------------------------------------------------
#define AROW 72   // shorts per LDS row (64 k' + 8 pad)

__global__ __launch_bounds__(256, 4)
void conv_mfma_kernel(const float* __restrict__ Xm, const float* __restrict__ Xr,
                      const unsigned short* __restrict__ Wimg,
                      float* __restrict__ Ym, float* __restrict__ Yr) {
    const int mat = blockIdx.y;
    const float* __restrict__ X = mat ? Xr : Xm;
    float* __restrict__ Y       = mat ? Yr : Ym;

    __shared__ unsigned short AT[128 * AROW];   // [px][k'] 18 KB
    __shared__ unsigned short BT[128 * AROW];   // [d][k']  18 KB

    const int t  = threadIdx.x;
    const int wv = t >> 6;
    const int l  = t & 63;
    const int wm = (wv >> 1) * 64;   // wave's px-quadrant
    const int wn = (wv & 1) * 64;    // wave's d-quadrant
    const int lr = l & 15;
    const int lq = l >> 4;
    const int p_base = blockIdx.x * 128;

    const int px = t >> 1, ahalf = t & 1;   // A staging: 2 thr/px, 8 c each

    f32x4 acc[4][4] = {};

    const float* xbase = X + (size_t)(p_base + px) * CC + ahalf * 8;

    // ---- prologue: prefetch X chunk 0 into registers ----
    float4 xa0 = *(const float4*)(xbase);
    float4 xa1 = *(const float4*)(xbase + 4);

    for (int kc16 = 0; kc16 < 8; ++kc16) {   // 8 chunks of 16 c (64 k')
        __syncthreads();                     // prev MFMA done; X prefetch drained
        // ---- issue W-image DMA for this chunk (drained at next barrier) ----
        {
            const unsigned short* imgrow = Wimg + (size_t)(mat * 8 + kc16) * 9216;
            for (int i = wv; i < 18; i += 4) {
                __builtin_amdgcn_global_load_lds(
                    (const __attribute__((address_space(1))) void*)(imgrow + i * 512 + l * 8),
                    (__attribute__((address_space(3))) void*)&BT[i * 512],
                    16, 0, 0);
            }
        }
        // ---- stage A from regs (fp32 -> [h,h,l,l] bf16) ----
        {
            unsigned short* arow = &AT[px * AROW + ahalf * 32];
            {
                uint2 a0 = split_aa(xa0.x), a1 = split_aa(xa0.y),
                      a2 = split_aa(xa0.z), a3 = split_aa(xa0.w);
                *(uint4*)(arow)     = make_uint4(a0.x, a0.y, a1.x, a1.y);
                *(uint4*)(arow + 8) = make_uint4(a2.x, a2.y, a3.x, a3.y);
            }
            {
                uint2 a0 = split_aa(xa1.x), a1 = split_aa(xa1.y),
                      a2 = split_aa(xa1.z), a3 = split_aa(xa1.w);
                *(uint4*)(arow + 16) = make_uint4(a0.x, a0.y, a1.x, a1.y);
                *(uint4*)(arow + 24) = make_uint4(a2.x, a2.y, a3.x, a3.y);
            }
        }
        __syncthreads();                     // drains W DMA + A ds_writes
        // ---- prefetch X chunk kc16+1 (overlaps MFMA below) ----
        if (kc16 < 7) {
            const float* xp = xbase + kc16 * 16 + 16;
            xa0 = *(const float4*)(xp);
            xa1 = *(const float4*)(xp + 4);
        }
        // ---- MFMA: 2 k-steps of 32 ----
#pragma unroll
        for (int ks = 0; ks < 2; ++ks) {
            bf16x8 af[4], bfr[4];
#pragma unroll
            for (int mi = 0; mi < 4; ++mi)
                af[mi] = *(const bf16x8*)&AT[(wm + mi * 16 + lr) * AROW + ks * 32 + lq * 8];
#pragma unroll
            for (int ni = 0; ni < 4; ++ni)
                bfr[ni] = *(const bf16x8*)&BT[(wn + ni * 16 + lr) * AROW + ks * 32 + lq * 8];
#pragma unroll
            for (int mi = 0; mi < 4; ++mi)
#pragma unroll
                for (int ni = 0; ni < 4; ++ni)
                    acc[mi][ni] = __builtin_amdgcn_mfma_f32_16x16x32_bf16(
                        af[mi], bfr[ni], acc[mi][ni], 0, 0, 0);
        }
    }

    // epilogue: C/D layout col=lane&15, row=(lane>>4)*4+reg
#pragma unroll
    for (int mi = 0; mi < 4; ++mi)
#pragma unroll
        for (int ni = 0; ni < 4; ++ni)
#pragma unroll
            for (int reg = 0; reg < 4; ++reg) {
                const int row = p_base + wm + mi * 16 + lq * 4 + reg;
                Y[(size_t)row * CC + wn + ni * 16 + lr] = acc[mi][ni][reg];
            }
}

// ---------------------------------------------------------------------------
// Kernel 2: local 5x5 attention.
// v8: pair-pixels with EIGHT channel-parts (512 thr: 64 pairs x 8 parts).
// v7's 4-part pair needed ~140 VGPR -> 2 waves/SIMD cap (8 waves/CU,
// occupancy 9.4%) which cancelled the pair-pixel 0.6x LDS-read win.
// 8 parts: each lane owns 4 ch/chunk (1 float4 group) -> q regs and
// transient K regs halve; est ~95-110 VGPR <= 128 -> 16 waves/CU AND the
// 14.4us pair read floor. Logit combine = 3 shfl_xor (1,2,4) within the
// pair's 8-lane group. Staging addresses hoisted: 4 pixel indices
// precomputed once (kills the /21+clamp chain per phase).
// LDS 2x8x257x16B = 65.8KB -> 2 blocks/CU; grid 512 = exactly 2/CU.
// GSLOT=257 (odd): group stride 4112B -> parts at 4-bank skew, ~2-way max.
// OOB: staged addrs clamped; logits of invalid neighbors = 0; their
// softmax weights = 0 (exact zero-pad semantics).
// ---------------------------------------------------------------------------
#define TH 8
#define TW 16
#define HROW 21        // padded halo row width in float4 (20 real + 1 pad)
#define GSLOT 257      // 12*21=252 real slots + pad (odd => bank skew)
#define NSLOT (8 * GSLOT)   // 2056 slots per buffer

__global__ __launch_bounds__(512, 4)
void attn_tile_kernel(const float* __restrict__ qm, const float* __restrict__ kr,
                      const float* __restrict__ vv, float* __restrict__ out) {
    __shared__ float4 KS[2][NSLOT];   // 65.8 KB

    const int t    = threadIdx.x;
    const int wid  = t >> 6;          // wave 0..7 == staging group
    const int ln   = t & 63;
    const int part = t & 7;           // channel-eighth owned by this lane
    const int pxi  = t >> 3;          // pixel-PAIR 0..63 within tile

    const int bi = blockIdx.x >> 7;           // batch
    const int ty = (blockIdx.x >> 3) & 15;    // 16 tile-rows of 8
    const int tx = blockIdx.x & 7;            // 8 tile-cols of 16
    const int h0 = ty * TH, w0 = tx * TW;
    const int r  = pxi >> 3;                  // row 0..7
    const int c2 = (pxi & 7) * 2;             // left col of pair: 0,2,..,14
    const int h = h0 + r, w = w0 + c2;
    const int gbase = bi * HH * WW;
    const int pix0 = gbase + h * WW + w;      // left pixel
    const int pix1 = pix0 + 1;                // right pixel (w+1 <= 127)

    // 25-bit validity masks for the two pixels' windows
    unsigned vm0 = 0, vm1 = 0;
#pragma unroll
    for (int dy = 0; dy < 5; ++dy)
#pragma unroll
        for (int dx = 0; dx < 5; ++dx) {
            const int hh = h + dy - 2;
            const int ww0 = w + dx - 2, ww1 = w + 1 + dx - 2;
            if ((unsigned)hh < (unsigned)HH && (unsigned)ww0 < (unsigned)WW)
                vm0 |= 1u << (dy * 5 + dx);
            if ((unsigned)hh < (unsigned)HH && (unsigned)ww1 < (unsigned)WW)
                vm1 |= 1u << (dy * 5 + dx);
        }

    // hoisted staging pixel indices (wave wid stages group wid; 4 chunks of
    // 64 slots cover 252 real halo slots + 4 clamped pads). Named scalars,
    // not an array (round-5 lesson: address-taken arrays spill).
    int spx0, spx1, spx2, spx3;
    {
#pragma unroll
        for (int i = 0; i < 4; ++i) {
            const int slot = i * 64 + ln;
            const int py  = slot / 21;
            const int pxx = slot - py * 21;
            int hh = h0 + py - 2;  hh = hh < 0 ? 0 : (hh > HH - 1 ? HH - 1 : hh);
            int ww = w0 + pxx - 2; ww = ww < 0 ? 0 : (ww > WW - 1 ? WW - 1 : ww);
            const int pv = gbase + hh * WW + ww;
            if (i == 0) spx0 = pv; else if (i == 1) spx1 = pv;
            else if (i == 2) spx2 = pv; else spx3 = pv;
        }
    }

    auto stage = [&](int p, int buf) {
        const float* src = (p < 4) ? kr : vv;
        const int ld = (p < 4) ? CC : BIN;
        const int ch = ((p < 4) ? p * 32 : (p - 4) * 32) + wid * 4;
        __builtin_amdgcn_global_load_lds(
            (const __attribute__((address_space(1))) void*)(src + (size_t)spx0 * ld + ch),
            (__attribute__((address_space(3))) void*)&KS[buf][wid * GSLOT], 16, 0, 0);
        __builtin_amdgcn_global_load_lds(
            (const __attribute__((address_space(1))) void*)(src + (size_t)spx1 * ld + ch),
            (__attribute__((address_space(3))) void*)&KS[buf][wid * GSLOT + 64], 16, 0, 0);
        __builtin_amdgcn_global_load_lds(
            (const __attribute__((address_space(1))) void*)(src + (size_t)spx2 * ld + ch),
            (__attribute__((address_space(3))) void*)&KS[buf][wid * GSLOT + 128], 16, 0, 0);
        __builtin_amdgcn_global_load_lds(
            (const __attribute__((address_space(1))) void*)(src + (size_t)spx3 * ld + ch),
            (__attribute__((address_space(3))) void*)&KS[buf][wid * GSLOT + 192], 16, 0, 0);
    };

    float lg0[25], lg1[25];
#pragma unroll
    for (int i = 0; i < 25; ++i) { lg0[i] = 0.0f; lg1[i] = 0.0f; }

    stage(0, 0);
    __syncthreads();

    for (int p = 0; p < 6; ++p) {
        if (p < 5) stage(p + 1, (p + 1) & 1);   // prefetch into other buffer
        const float4* Bp = KS[p & 1] + part * GSLOT;
        if (p < 4) {
            // ---- logits chunk: 32 channels, this lane's 4, both pixels ----
            const float4 q0 = *(const float4*)(qm + (size_t)pix0 * CC + p * 32 + part * 4);
            const float4 q1 = *(const float4*)(qm + (size_t)pix1 * CC + p * 32 + part * 4);
            // union of the two 5x5 windows: 5 rows x 6 cols
#pragma unroll
            for (int dy = 0; dy < 5; ++dy)
#pragma unroll
                for (int du = 0; du < 6; ++du) {
                    const int hp = (r + dy) * HROW + (c2 + du);
                    const float4 k = Bp[hp];
                    if (du < 5)
                        lg0[dy * 5 + du] += q0.x * k.x + q0.y * k.y +
                                            q0.z * k.z + q0.w * k.w;
                    if (du > 0)
                        lg1[dy * 5 + du - 1] += q1.x * k.x + q1.y * k.y +
                                                q1.z * k.z + q1.w * k.w;
                }
        } else {
            if (p == 4) {
                // combine the 8 channel-parts' partial logits (lanes ^1,^2,^4)
#pragma unroll
                for (int kk = 0; kk < 25; ++kk) {
                    float v0 = lg0[kk];
                    v0 += __shfl_xor(v0, 1);
                    v0 += __shfl_xor(v0, 2);
                    v0 += __shfl_xor(v0, 4);
                    lg0[kk] = v0;
                    float v1 = lg1[kk];
                    v1 += __shfl_xor(v1, 1);
                    v1 += __shfl_xor(v1, 2);
                    v1 += __shfl_xor(v1, 4);
                    lg1[kk] = v1;
                }
                // mask OOB logits to 0, softmax, zero OOB weights (both px)
#pragma unroll
                for (int kk = 0; kk < 25; ++kk) {
                    if (!((vm0 >> kk) & 1)) lg0[kk] = 0.0f;
                    if (!((vm1 >> kk) & 1)) lg1[kk] = 0.0f;
                }
                float mx0 = lg0[0], mx1 = lg1[0];
#pragma unroll
                for (int kk = 1; kk < 25; ++kk) {
                    mx0 = fmaxf(mx0, lg0[kk]);
                    mx1 = fmaxf(mx1, lg1[kk]);
                }
                float sum0 = 0.0f, sum1 = 0.0f;
#pragma unroll
                for (int kk = 0; kk < 25; ++kk) {
                    lg0[kk] = __expf(lg0[kk] - mx0); sum0 += lg0[kk];
                    lg1[kk] = __expf(lg1[kk] - mx1); sum1 += lg1[kk];
                }
                const float inv0 = 1.0f / sum0, inv1 = 1.0f / sum1;
#pragma unroll
                for (int kk = 0; kk < 25; ++kk) {
                    lg0[kk] = ((vm0 >> kk) & 1) ? lg0[kk] * inv0 : 0.0f;
                    lg1[kk] = ((vm1 >> kk) & 1) ? lg1[kk] * inv1 : 0.0f;
                }
            }
            // ---- value-mix chunk: 32 bins, this lane's 4, both pixels ----
            float4 a0 = make_float4(0.f, 0.f, 0.f, 0.f);
            float4 a1 = make_float4(0.f, 0.f, 0.f, 0.f);
#pragma unroll
            for (int dy = 0; dy < 5; ++dy)
#pragma unroll
                for (int du = 0; du < 6; ++du) {
                    const int hp = (r + dy) * HROW + (c2 + du);
                    const float4 v = Bp[hp];
                    if (du < 5) {
                        const float wg = lg0[dy * 5 + du];
                        a0.x += wg * v.x; a0.y += wg * v.y;
                        a0.z += wg * v.z; a0.w += wg * v.w;
                    }
                    if (du > 0) {
                        const float wg = lg1[dy * 5 + du - 1];
                        a1.x += wg * v.x; a1.y += wg * v.y;
                        a1.z += wg * v.z; a1.w += wg * v.w;
                    }
                }
            *(float4*)(out + (size_t)pix0 * BIN + (p - 4) * 32 + part * 4) = a0;
            *(float4*)(out + (size_t)pix1 * BIN + (p - 4) * 32 + part * 4) = a1;
        }
        __syncthreads();
    }
}

extern "C" void kernel_launch(void* const* d_in, const int* in_sizes, int n_in,
                              void* d_out, int out_size, void* d_ws, size_t ws_size,
                              hipStream_t stream) {
    const float* main_in   = (const float*)d_in[0];
    const float* ref_in    = (const float*)d_in[1];
    const float* ref_value = (const float*)d_in[2];
    const float* W_main    = (const float*)d_in[3];
    const float* W_ref     = (const float*)d_in[4];
    float* out = (float*)d_out;

    float* conv_main = (float*)d_ws;                         // 32 MB
    float* conv_ref  = conv_main + (size_t)NPIX * CC;        // 32 MB

    // W pre-split image (288KB) in d_out scratch: wsplit writes it, conv
    // reads it, attn overwrites d_out afterwards (stream-ordered).
    unsigned short* Wimg = (unsigned short*)d_out;
    wsplit_kernel<<<8, 256, 0, stream>>>(W_main, W_ref, Wimg);

    dim3 gconv(NPIX / 128, 2);   // 1024 blocks = 4/CU
    conv_mfma_kernel<<<gconv, 256, 0, stream>>>(main_in, ref_in, Wimg,
                                                conv_main, conv_ref);

    // 512 blocks = 2/CU: one 8x16 tile, 2 adjacent px/thread, 8 parts
    attn_tile_kernel<<<512, 512, 0, stream>>>(conv_main, conv_ref, ref_value, out);
}

// Round 10
// 180.027 us; speedup vs baseline: 1.2477x; 1.2477x over previous
//
#include <hip/hip_runtime.h>

// Problem dims (fixed by setup_inputs)
#define BATCH 4
#define HH 128
#define WW 128
#define CC 128
#define BIN 64
#define NPIX (BATCH * HH * WW)   // 65536

typedef short bf16x8 __attribute__((ext_vector_type(8)));
typedef float f32x4 __attribute__((ext_vector_type(4)));

// round-to-nearest-even bf16 bits of f
__device__ __forceinline__ unsigned bf_hi(float f) {
    unsigned u = __float_as_uint(f);
    return (u + 0x7fffu + ((u >> 16) & 1u)) >> 16;
}
// A-operand split: per c, k' slots [4c..4c+3] = [xh, xh, xl, xl]
__device__ __forceinline__ uint2 split_aa(float f) {
    unsigned hb = bf_hi(f);
    float lo = f - __uint_as_float(hb << 16);
    unsigned lb = bf_hi(lo);
    return make_uint2(hb | (hb << 16), lb | (lb << 16));
}
// B-operand split: per c, k' slots = [wh, wl, wh, wl] -> same uint twice
__device__ __forceinline__ unsigned split_b(float f) {
    unsigned hb = bf_hi(f);
    float lo = f - __uint_as_float(hb << 16);
    unsigned lb = bf_hi(lo);
    return hb | (lb << 16);
}

// ---------------------------------------------------------------------------
// Kernel 0: W pre-split. W_main/W_ref (128x128 fp32) -> split-bf16 BT LDS
// images: per matrix 8 chunks x [128 d][72 shorts] (64 k' + 8 zero pad),
// exactly the BT layout conv reads. 288KB, written into d_out scratch
// (conv consumes it before attn overwrites d_out).
// ---------------------------------------------------------------------------
__global__ __launch_bounds__(256)
void wsplit_kernel(const float* __restrict__ Wm, const float* __restrict__ Wr,
                   unsigned short* __restrict__ img) {
    const int row = blockIdx.x * 256 + threadIdx.x;   // 0..2047
    const int m = row >> 10;                          // matrix
    const int rr = row & 1023;
    const int chunk = rr >> 7, d = rr & 127;
    const float* W = m ? Wr : Wm;
    unsigned short* rp = img + ((size_t)(m * 8 + chunk) * 128 + d) * 72;
#pragma unroll
    for (int cg = 0; cg < 4; ++cg) {
        const int c = chunk * 16 + cg * 4;
        unsigned b0 = split_b(W[(size_t)(c + 0) * CC + d]);
        unsigned b1 = split_b(W[(size_t)(c + 1) * CC + d]);
        unsigned b2 = split_b(W[(size_t)(c + 2) * CC + d]);
        unsigned b3 = split_b(W[(size_t)(c + 3) * CC + d]);
        *(uint4*)(rp + cg * 16)     = make_uint4(b0, b0, b1, b1);
        *(uint4*)(rp + cg * 16 + 8) = make_uint4(b2, b2, b3, b3);
    }
    *(uint4*)(rp + 64) = make_uint4(0, 0, 0, 0);      // pad
}

// ---------------------------------------------------------------------------
// Kernel 1: 1x1 conv == GEMM via split-bf16 MFMA.
// B-tile from the pre-split W image via 18x global_load_lds (L2-hot,
// hidden under A-staging). A-staging depth-1 register prefetch,
// straight-line (no address-taken arrays). LDS 36.8KB -> 4 blocks/CU.
// ---------------------------------------------------------------------------
#define AROW 72   // shorts per LDS row (64 k' + 8 pad)

__global__ __launch_bounds__(256, 4)
void conv_mfma_kernel(const float* __restrict__ Xm, const float* __restrict__ Xr,
                      const unsigned short* __restrict__ Wimg,
                      float* __restrict__ Ym, float* __restrict__ Yr) {
    const int mat = blockIdx.y;
    const float* __restrict__ X = mat ? Xr : Xm;
    float* __restrict__ Y       = mat ? Yr : Ym;

    __shared__ unsigned short AT[128 * AROW];   // [px][k'] 18 KB
    __shared__ unsigned short BT[128 * AROW];   // [d][k']  18 KB

    const int t  = threadIdx.x;
    const int wv = t >> 6;
    const int l  = t & 63;
    const int wm = (wv >> 1) * 64;   // wave's px-quadrant
    const int wn = (wv & 1) * 64;    // wave's d-quadrant
    const int lr = l & 15;
    const int lq = l >> 4;
    const int p_base = blockIdx.x * 128;

    const int px = t >> 1, ahalf = t & 1;   // A staging: 2 thr/px, 8 c each

    f32x4 acc[4][4] = {};

    const float* xbase = X + (size_t)(p_base + px) * CC + ahalf * 8;

    // ---- prologue: prefetch X chunk 0 into registers ----
    float4 xa0 = *(const float4*)(xbase);
    float4 xa1 = *(const float4*)(xbase + 4);

    for (int kc16 = 0; kc16 < 8; ++kc16) {   // 8 chunks of 16 c (64 k')
        __syncthreads();                     // prev MFMA done; X prefetch drained
        // ---- issue W-image DMA for this chunk (drained at next barrier) ----
        {
            const unsigned short* imgrow = Wimg + (size_t)(mat * 8 + kc16) * 9216;
            for (int i = wv; i < 18; i += 4) {
                __builtin_amdgcn_global_load_lds(
                    (const __attribute__((address_space(1))) void*)(imgrow + i * 512 + l * 8),
                    (__attribute__((address_space(3))) void*)&BT[i * 512],
                    16, 0, 0);
            }
        }
        // ---- stage A from regs (fp32 -> [h,h,l,l] bf16) ----
        {
            unsigned short* arow = &AT[px * AROW + ahalf * 32];
            {
                uint2 a0 = split_aa(xa0.x), a1 = split_aa(xa0.y),
                      a2 = split_aa(xa0.z), a3 = split_aa(xa0.w);
                *(uint4*)(arow)     = make_uint4(a0.x, a0.y, a1.x, a1.y);
                *(uint4*)(arow + 8) = make_uint4(a2.x, a2.y, a3.x, a3.y);
            }
            {
                uint2 a0 = split_aa(xa1.x), a1 = split_aa(xa1.y),
                      a2 = split_aa(xa1.z), a3 = split_aa(xa1.w);
                *(uint4*)(arow + 16) = make_uint4(a0.x, a0.y, a1.x, a1.y);
                *(uint4*)(arow + 24) = make_uint4(a2.x, a2.y, a3.x, a3.y);
            }
        }
        __syncthreads();                     // drains W DMA + A ds_writes
        // ---- prefetch X chunk kc16+1 (overlaps MFMA below) ----
        if (kc16 < 7) {
            const float* xp = xbase + kc16 * 16 + 16;
            xa0 = *(const float4*)(xp);
            xa1 = *(const float4*)(xp + 4);
        }
        // ---- MFMA: 2 k-steps of 32 ----
#pragma unroll
        for (int ks = 0; ks < 2; ++ks) {
            bf16x8 af[4], bfr[4];
#pragma unroll
            for (int mi = 0; mi < 4; ++mi)
                af[mi] = *(const bf16x8*)&AT[(wm + mi * 16 + lr) * AROW + ks * 32 + lq * 8];
#pragma unroll
            for (int ni = 0; ni < 4; ++ni)
                bfr[ni] = *(const bf16x8*)&BT[(wn + ni * 16 + lr) * AROW + ks * 32 + lq * 8];
#pragma unroll
            for (int mi = 0; mi < 4; ++mi)
#pragma unroll
                for (int ni = 0; ni < 4; ++ni)
                    acc[mi][ni] = __builtin_amdgcn_mfma_f32_16x16x32_bf16(
                        af[mi], bfr[ni], acc[mi][ni], 0, 0, 0);
        }
    }

    // epilogue: C/D layout col=lane&15, row=(lane>>4)*4+reg
#pragma unroll
    for (int mi = 0; mi < 4; ++mi)
#pragma unroll
        for (int ni = 0; ni < 4; ++ni)
#pragma unroll
            for (int reg = 0; reg < 4; ++reg) {
                const int row = p_base + wm + mi * 16 + lq * 4 + reg;
                Y[(size_t)row * CC + wn + ni * 16 + lr] = acc[mi][ni][reg];
            }
}

// ---------------------------------------------------------------------------
// Kernel 2: local 5x5 attention.
// v9 = v8 with __launch_bounds__(512, 2). v8's (512,4) = 8 waves/SIMD
// budget = 64 VGPR -> catastrophic spill (WRITE 177MB, 92us). (512,2) =
// 4 waves/SIMD = 128-VGPR budget, matching the ~110-125 pressure of the
// 8-part pair kernel; LDS caps residency at 2 blocks/CU regardless.
// Structure: 64 pixel-PAIRS x 8 channel-parts (512 thr). Pair windows
// share 4/5 cols -> union read 5x6=30 vectors vs 50 (LDS reads x0.6).
// Logit combine = 3 shfl_xor (1,2,4). Staging pixel indices hoisted.
// GSLOT=257 (odd): 4112B group stride -> bank-skewed parts, ~2-way max.
// OOB: staged addrs clamped; logits of invalid neighbors = 0; their
// softmax weights = 0 (exact zero-pad semantics).
// ---------------------------------------------------------------------------
#define TH 8
#define TW 16
#define HROW 21        // padded halo row width in float4 (20 real + 1 pad)
#define GSLOT 257      // 12*21=252 real slots + pad (odd => bank skew)
#define NSLOT (8 * GSLOT)   // 2056 slots per buffer

__global__ __launch_bounds__(512, 2)
void attn_tile_kernel(const float* __restrict__ qm, const float* __restrict__ kr,
                      const float* __restrict__ vv, float* __restrict__ out) {
    __shared__ float4 KS[2][NSLOT];   // 65.8 KB

    const int t    = threadIdx.x;
    const int wid  = t >> 6;          // wave 0..7 == staging group
    const int ln   = t & 63;
    const int part = t & 7;           // channel-eighth owned by this lane
    const int pxi  = t >> 3;          // pixel-PAIR 0..63 within tile

    const int bi = blockIdx.x >> 7;           // batch
    const int ty = (blockIdx.x >> 3) & 15;    // 16 tile-rows of 8
    const int tx = blockIdx.x & 7;            // 8 tile-cols of 16
    const int h0 = ty * TH, w0 = tx * TW;
    const int r  = pxi >> 3;                  // row 0..7
    const int c2 = (pxi & 7) * 2;             // left col of pair: 0,2,..,14
    const int h = h0 + r, w = w0 + c2;
    const int gbase = bi * HH * WW;
    const int pix0 = gbase + h * WW + w;      // left pixel
    const int pix1 = pix0 + 1;                // right pixel (w+1 <= 127)

    // 25-bit validity masks for the two pixels' windows
    unsigned vm0 = 0, vm1 = 0;
#pragma unroll
    for (int dy = 0; dy < 5; ++dy)
#pragma unroll
        for (int dx = 0; dx < 5; ++dx) {
            const int hh = h + dy - 2;
            const int ww0 = w + dx - 2, ww1 = w + 1 + dx - 2;
            if ((unsigned)hh < (unsigned)HH && (unsigned)ww0 < (unsigned)WW)
                vm0 |= 1u << (dy * 5 + dx);
            if ((unsigned)hh < (unsigned)HH && (unsigned)ww1 < (unsigned)WW)
                vm1 |= 1u << (dy * 5 + dx);
        }

    // hoisted staging pixel indices (wave wid stages group wid; 4 chunks of
    // 64 slots cover 252 real halo slots + 4 clamped pads). Named scalars,
    // not an array (round-5 lesson: address-taken arrays spill).
    int spx0, spx1, spx2, spx3;
    {
#pragma unroll
        for (int i = 0; i < 4; ++i) {
            const int slot = i * 64 + ln;
            const int py  = slot / 21;
            const int pxx = slot - py * 21;
            int hh = h0 + py - 2;  hh = hh < 0 ? 0 : (hh > HH - 1 ? HH - 1 : hh);
            int ww = w0 + pxx - 2; ww = ww < 0 ? 0 : (ww > WW - 1 ? WW - 1 : ww);
            const int pv = gbase + hh * WW + ww;
            if (i == 0) spx0 = pv; else if (i == 1) spx1 = pv;
            else if (i == 2) spx2 = pv; else spx3 = pv;
        }
    }

    auto stage = [&](int p, int buf) {
        const float* src = (p < 4) ? kr : vv;
        const int ld = (p < 4) ? CC : BIN;
        const int ch = ((p < 4) ? p * 32 : (p - 4) * 32) + wid * 4;
        __builtin_amdgcn_global_load_lds(
            (const __attribute__((address_space(1))) void*)(src + (size_t)spx0 * ld + ch),
            (__attribute__((address_space(3))) void*)&KS[buf][wid * GSLOT], 16, 0, 0);
        __builtin_amdgcn_global_load_lds(
            (const __attribute__((address_space(1))) void*)(src + (size_t)spx1 * ld + ch),
            (__attribute__((address_space(3))) void*)&KS[buf][wid * GSLOT + 64], 16, 0, 0);
        __builtin_amdgcn_global_load_lds(
            (const __attribute__((address_space(1))) void*)(src + (size_t)spx2 * ld + ch),
            (__attribute__((address_space(3))) void*)&KS[buf][wid * GSLOT + 128], 16, 0, 0);
        __builtin_amdgcn_global_load_lds(
            (const __attribute__((address_space(1))) void*)(src + (size_t)spx3 * ld + ch),
            (__attribute__((address_space(3))) void*)&KS[buf][wid * GSLOT + 192], 16, 0, 0);
    };

    float lg0[25], lg1[25];
#pragma unroll
    for (int i = 0; i < 25; ++i) { lg0[i] = 0.0f; lg1[i] = 0.0f; }

    stage(0, 0);
    __syncthreads();

    for (int p = 0; p < 6; ++p) {
        if (p < 5) stage(p + 1, (p + 1) & 1);   // prefetch into other buffer
        const float4* Bp = KS[p & 1] + part * GSLOT;
        if (p < 4) {
            // ---- logits chunk: 32 channels, this lane's 4, both pixels ----
            const float4 q0 = *(const float4*)(qm + (size_t)pix0 * CC + p * 32 + part * 4);
            const float4 q1 = *(const float4*)(qm + (size_t)pix1 * CC + p * 32 + part * 4);
            // union of the two 5x5 windows: 5 rows x 6 cols
#pragma unroll
            for (int dy = 0; dy < 5; ++dy)
#pragma unroll
                for (int du = 0; du < 6; ++du) {
                    const int hp = (r + dy) * HROW + (c2 + du);
                    const float4 k = Bp[hp];
                    if (du < 5)
                        lg0[dy * 5 + du] += q0.x * k.x + q0.y * k.y +
                                            q0.z * k.z + q0.w * k.w;
                    if (du > 0)
                        lg1[dy * 5 + du - 1] += q1.x * k.x + q1.y * k.y +
                                                q1.z * k.z + q1.w * k.w;
                }
        } else {
            if (p == 4) {
                // combine the 8 channel-parts' partial logits (lanes ^1,^2,^4)
#pragma unroll
                for (int kk = 0; kk < 25; ++kk) {
                    float v0 = lg0[kk];
                    v0 += __shfl_xor(v0, 1);
                    v0 += __shfl_xor(v0, 2);
                    v0 += __shfl_xor(v0, 4);
                    lg0[kk] = v0;
                    float v1 = lg1[kk];
                    v1 += __shfl_xor(v1, 1);
                    v1 += __shfl_xor(v1, 2);
                    v1 += __shfl_xor(v1, 4);
                    lg1[kk] = v1;
                }
                // mask OOB logits to 0, softmax, zero OOB weights (both px)
#pragma unroll
                for (int kk = 0; kk < 25; ++kk) {
                    if (!((vm0 >> kk) & 1)) lg0[kk] = 0.0f;
                    if (!((vm1 >> kk) & 1)) lg1[kk] = 0.0f;
                }
                float mx0 = lg0[0], mx1 = lg1[0];
#pragma unroll
                for (int kk = 1; kk < 25; ++kk) {
                    mx0 = fmaxf(mx0, lg0[kk]);
                    mx1 = fmaxf(mx1, lg1[kk]);
                }
                float sum0 = 0.0f, sum1 = 0.0f;
#pragma unroll
                for (int kk = 0; kk < 25; ++kk) {
                    lg0[kk] = __expf(lg0[kk] - mx0); sum0 += lg0[kk];
                    lg1[kk] = __expf(lg1[kk] - mx1); sum1 += lg1[kk];
                }
                const float inv0 = 1.0f / sum0, inv1 = 1.0f / sum1;
#pragma unroll
                for (int kk = 0; kk < 25; ++kk) {
                    lg0[kk] = ((vm0 >> kk) & 1) ? lg0[kk] * inv0 : 0.0f;
                    lg1[kk] = ((vm1 >> kk) & 1) ? lg1[kk] * inv1 : 0.0f;
                }
            }
            // ---- value-mix chunk: 32 bins, this lane's 4, both pixels ----
            float4 a0 = make_float4(0.f, 0.f, 0.f, 0.f);
            float4 a1 = make_float4(0.f, 0.f, 0.f, 0.f);
#pragma unroll
            for (int dy = 0; dy < 5; ++dy)
#pragma unroll
                for (int du = 0; du < 6; ++du) {
                    const int hp = (r + dy) * HROW + (c2 + du);
                    const float4 v = Bp[hp];
                    if (du < 5) {
                        const float wg = lg0[dy * 5 + du];
                        a0.x += wg * v.x; a0.y += wg * v.y;
                        a0.z += wg * v.z; a0.w += wg * v.w;
                    }
                    if (du > 0) {
                        const float wg = lg1[dy * 5 + du - 1];
                        a1.x += wg * v.x; a1.y += wg * v.y;
                        a1.z += wg * v.z; a1.w += wg * v.w;
                    }
                }
            *(float4*)(out + (size_t)pix0 * BIN + (p - 4) * 32 + part * 4) = a0;
            *(float4*)(out + (size_t)pix1 * BIN + (p - 4) * 32 + part * 4) = a1;
        }
        __syncthreads();
    }
}

extern "C" void kernel_launch(void* const* d_in, const int* in_sizes, int n_in,
                              void* d_out, int out_size, void* d_ws, size_t ws_size,
                              hipStream_t stream) {
    const float* main_in   = (const float*)d_in[0];
    const float* ref_in    = (const float*)d_in[1];
    const float* ref_value = (const float*)d_in[2];
    const float* W_main    = (const float*)d_in[3];
    const float* W_ref     = (const float*)d_in[4];
    float* out = (float*)d_out;

    float* conv_main = (float*)d_ws;                         // 32 MB
    float* conv_ref  = conv_main + (size_t)NPIX * CC;        // 32 MB

    // W pre-split image (288KB) in d_out scratch: wsplit writes it, conv
    // reads it, attn overwrites d_out afterwards (stream-ordered).
    unsigned short* Wimg = (unsigned short*)d_out;
    wsplit_kernel<<<8, 256, 0, stream>>>(W_main, W_ref, Wimg);

    dim3 gconv(NPIX / 128, 2);   // 1024 blocks = 4/CU
    conv_mfma_kernel<<<gconv, 256, 0, stream>>>(main_in, ref_in, Wimg,
                                                conv_main, conv_ref);

    // 512 blocks = 2/CU: one 8x16 tile, 2 adjacent px/thread, 8 parts
    attn_tile_kernel<<<512, 512, 0, stream>>>(conv_main, conv_ref, ref_value, out);
}